// Round 17
// baseline (437.071 us; speedup 1.0000x reference)
//
#include <hip/hip_runtime.h>
#include <hip/hip_bf16.h>

// NoisyActLin: y = fakequant(x) @ fakequant(W).T + bias
// x: [4,2048,2048] f32 -> M=8192, K=2048 ; W: [8192,2048] f32 -> N=8192
// out: [8192, 8192] f32
//
// R17: B BYPASSES LDS. R15/R16 closed the model: the LDS port (~85 B/cyc/CU)
// is the wall — even m201's template is port-bound (2981 cyc/K-tile = 260KB
// LDS traffic / 85). Removing B's frag reads (65KB) + staging writes (32KB)
// per K-tile makes the kernel MFMA-bound (port 163KB -> 245k cyc/CU < MFMA
// 277k cyc/CU). B frags load straight from global (each lane 16 contiguous
// B; each 64B line fully consumed by 4 lanes; B panels L2/L3-resident under
// the R13 lockstep XCD mapping), double-buffered one K-tile ahead; the
// compiler tracks these loads and inserts counted vmcnt. LDS = A only, 64KB
// -> 2 blocks/CU. VMC(0)-before-BAR keeps the cross-wave landing guarantee.

using f16x8 = __attribute__((ext_vector_type(8))) _Float16;
using f32x4 = __attribute__((ext_vector_type(4))) float;

#define AS1 __attribute__((address_space(1)))
#define AS3 __attribute__((address_space(3)))

static __device__ __forceinline__ void gload_lds16(const void* g, void* l) {
    __builtin_amdgcn_global_load_lds((const AS1 void*)g, (AS3 void*)l, 16, 0, 0);
}

// ---------------- fused fake-quant: x elementwise + W per-row ----------------
__global__ __launch_bounds__(256) void quant_kernel(
    const float* __restrict__ X,
    const float* __restrict__ las, const float* __restrict__ laq,
    const float* __restrict__ ab,
    const float* __restrict__ W, const float* __restrict__ lws,
    _Float16* __restrict__ Xq, _Float16* __restrict__ Wq) {
    constexpr int K = 2048;
    __shared__ float smn[4], smx[4];
    const int t = threadIdx.x;

    if (blockIdx.x < 8192) {
        const float ls = las[0], lq = laq[0];
        const float s = exp2f(ls);
        const float rs = exp2f(-ls);
        const float q = exp2f(lq);
        const float zp = rintf(ab[0] * rs * 2.0f) * 0.5f * s;  // ACT_GUARD=2
        const float lo = zp;
        const float hi = (zp + q) - s;

        const size_t base = ((size_t)blockIdx.x * 256 + t) * 8;
        float4 v0 = *(const float4*)&X[base];
        float4 v1 = *(const float4*)&X[base + 4];
        float vals[8] = {v0.x, v0.y, v0.z, v0.w, v1.x, v1.y, v1.z, v1.w};

        f16x8 out;
#pragma unroll
        for (int i = 0; i < 8; ++i) {
            float c = fminf(fmaxf(vals[i], lo), hi);
            float qx = rintf((c - zp) * rs);
            out[i] = (_Float16)(qx * s + zp);
        }
        *(f16x8*)&Xq[base] = out;
    } else {
        const int row = blockIdx.x - 8192;
        const float* w = W + (size_t)row * K;

        float4 v0 = ((const float4*)w)[t * 2];
        float4 v1 = ((const float4*)w)[t * 2 + 1];
        float vals[8] = {v0.x, v0.y, v0.z, v0.w, v1.x, v1.y, v1.z, v1.w};

        float mn = vals[0], mx = vals[0];
#pragma unroll
        for (int i = 1; i < 8; ++i) {
            mn = fminf(mn, vals[i]);
            mx = fmaxf(mx, vals[i]);
        }
#pragma unroll
        for (int off = 32; off >= 1; off >>= 1) {
            mn = fminf(mn, __shfl_xor(mn, off));
            mx = fmaxf(mx, __shfl_xor(mx, off));
        }
        if ((t & 63) == 0) { smn[t >> 6] = mn; smx[t >> 6] = mx; }
        __syncthreads();
        mn = fminf(fminf(smn[0], smn[1]), fminf(smn[2], smn[3]));
        mx = fmaxf(fmaxf(smx[0], smx[1]), fmaxf(smx[2], smx[3]));

        const float l = lws[row];
        const float ws = exp2f(l);
        const float rs = exp2f(-l);
        const float qwmin = rintf(mn * rs * 2.0f) * 0.5f * ws;  // WGT_GUARD=2
        const float qwmax = rintf(mx * rs * 2.0f) * 0.5f * ws;

        f16x8 out;
#pragma unroll
        for (int i = 0; i < 8; ++i) {
            float c = fminf(fmaxf(vals[i], qwmin), qwmax);
            float qw = rintf((c - qwmin) * rs);
            out[i] = (_Float16)(qw * ws + qwmin);
        }
        *(f16x8*)&Wq[(size_t)row * K + (size_t)t * 8] = out;
    }
}

// ---------------- GEMM: C[M][N] = A[M][K] * B[N][K]^T + bias ----------------
// LDS 64KB: A [db2][half2][128 rows][64 k] f16 (4 x 16KB slots). B in regs.
// 8 waves (2Mx4N), per-wave 128x64. 2 phases per K-tile kt (db=kt&1):
//  P_a: rd fA(rows 0-63 of wave half, 8 b128) ; stage (kt+1).A.h0 -> db^1 ;
//       LOADB fBnext(kt+1) [compiler-managed] ; BAR ; lgkm(0) ;
//       32 MFMA (m0-3 x n0-3 x ks0,1) ; BAR
//  P_b: rd fA(rows 64-127) ; stage (kt+1).A.h1 ; BAR ; lgkm(0) ;
//       32 MFMA (m4-7) ; VMC(0) ; BAR
// Landing: VMC(0) before tile-end BAR drains both A-stages (+B loads) =>
//   after BAR all waves' tile-(kt+1) data landed. (R6/R8 rule.)
// WAR: stage (kt+1).h targets db^1 slots whose readers (tile kt-1) drained
//   at tile kt-1's lgkm(0), >=2 barriers earlier.
// fA single-buffered (P_b's writes follow P_a's MFMAs in issue order).
__global__ __launch_bounds__(512, 2) void gemm_kernel(
    const _Float16* __restrict__ A, const _Float16* __restrict__ B,
    const float* __restrict__ bias, float* __restrict__ C) {
    constexpr int N = 8192, K = 2048;
    constexpr int KT = K / 64;          // 32 K-tiles, 16 iterations

    __shared__ char smem[65536];        // A only: [db2][half2] x 16KB

    // L2/L3-aware mapping (R13): XCD x owns A-band [4x,4x+4); bm fastest.
    const int bid = blockIdx.x;
    const int j = bid >> 3;
    const int bm = (bid & 7) * 4 + (j & 3);
    const int bn = j >> 2;

    const int t = threadIdx.x;
    const int lane = t & 63;
    const int wid = t >> 6;
    const int wr = wid >> 2;            // 0..1 (M half)
    const int wc = wid & 3;             // 0..3 (N quarter)
    const int l15 = lane & 15;
    const int lq = lane >> 4;

    // A staging: half-tile [128][64] f16 = 16KB, linear dest, pre-swizzled
    // source. T2 swizzle: byte ^= (row&7)<<4 (verified 0 conflicts).
    const int d0 = t * 16, d1 = d0 + 8192;
    const int r0 = d0 >> 7, c0 = (((d0 & 127) ^ (((d0 >> 7) & 7) << 4)) >> 1);
    const int r1 = d1 >> 7, c1 = (((d1 & 127) ^ (((d1 >> 7) & 7) << 4)) >> 1);
    const _Float16* Agb = A + (size_t)bm * 256 * K;
    // B per-wave base: row = bn*256 + wc*64 + n*16 + l15 ; k = kt*64+ks*32+lq*8
    const _Float16* Bw = B + (size_t)(bn * 256 + wc * 64 + l15) * K + lq * 8;

    // read-side swizzled k-col byte offsets (frag row&7 == l15&7)
    const int cp0 = (lq * 16) ^ ((l15 & 7) << 4);
    const int cp1 = cp0 ^ 64;

    f32x4 acc[8][4] = {};
    f16x8 fA[4][2], fBa[4][2], fBb[4][2];

#define STAGEH(DBS, H, KS) do {                                                \
        const _Float16* _g = Agb + (size_t)((H) * 128) * K + (size_t)(KS) * 64;\
        char* _l = smem + ((DBS) * 2 + (H)) * 16384;                           \
        gload_lds16(_g + (size_t)r0 * K + c0, _l + d0);                        \
        gload_lds16(_g + (size_t)r1 * K + c1, _l + d1);                        \
    } while (0)

#define LDAF(DBv, MLO) do {                                                    \
        const char* _s = smem + ((DBv) * 2 + wr) * 16384 + l15 * 128;          \
        _Pragma("unroll")                                                      \
        for (int _m = 0; _m < 4; ++_m) {                                       \
            fA[_m][0] = *(const f16x8*)(_s + ((MLO) + _m) * 2048 + cp0);       \
            fA[_m][1] = *(const f16x8*)(_s + ((MLO) + _m) * 2048 + cp1);       \
        }                                                                      \
    } while (0)

#define LOADB(FB, KS) do {                                                     \
        _Pragma("unroll")                                                      \
        for (int _n = 0; _n < 4; ++_n) {                                       \
            FB[_n][0] = *(const f16x8*)(Bw + (size_t)_n * 16 * K + (KS) * 64); \
            FB[_n][1] = *(const f16x8*)(Bw + (size_t)_n * 16 * K + (KS) * 64 + 32);\
        }                                                                      \
    } while (0)

#define HMFMA(MLO, FB) do {                                                    \
        _Pragma("unroll")                                                      \
        for (int _m = 0; _m < 4; ++_m)                                         \
            _Pragma("unroll")                                                  \
            for (int _n = 0; _n < 4; ++_n) {                                   \
                f32x4 _c = acc[(MLO) + _m][_n];                                \
                _c = __builtin_amdgcn_mfma_f32_16x16x32_f16(                   \
                    fA[_m][0], FB[_n][0], _c, 0, 0, 0);                        \
                _c = __builtin_amdgcn_mfma_f32_16x16x32_f16(                   \
                    fA[_m][1], FB[_n][1], _c, 0, 0, 0);                        \
                acc[(MLO) + _m][_n] = _c;                                      \
            }                                                                  \
    } while (0)

#define VMC0()  asm volatile("s_waitcnt vmcnt(0)" ::: "memory")
#define LG0()   asm volatile("s_waitcnt lgkmcnt(0)")
#define BAR()   __builtin_amdgcn_s_barrier()
#define PRIO(P) __builtin_amdgcn_s_setprio(P)

// one K-tile: 2 phases.
#define TILE(DBv, NXT, FBC, FBN) do {                                          \
        /* P_a */                                                              \
        LDAF(DBv, 0);                                                          \
        STAGEH((DBv) ^ 1, 0, NXT);                                             \
        LOADB(FBN, NXT);                                                       \
        BAR();                                                                 \
        LG0();                                                                 \
        PRIO(1); HMFMA(0, FBC); PRIO(0);                                       \
        BAR();                                                                 \
        /* P_b */                                                              \
        LDAF(DBv, 4);                                                          \
        STAGEH((DBv) ^ 1, 1, NXT);                                             \
        BAR();                                                                 \
        LG0();                                                                 \
        PRIO(1); HMFMA(4, FBC); PRIO(0);                                       \
        VMC0();                                                                \
        BAR();                                                                 \
    } while (0)

    // ---- prologue: stage tile0 A + load tile0 B; drain BEFORE barrier ----
    STAGEH(0, 0, 0);
    STAGEH(0, 1, 0);
    LOADB(fBa, 0);
    VMC0();
    BAR();

    for (int it = 0; it < KT / 2; ++it) {
        const int n1 = (2 * it + 1 < KT) ? 2 * it + 1 : KT - 1;
        const int n2 = (2 * it + 2 < KT) ? 2 * it + 2 : KT - 1;
        TILE(0, n1, fBa, fBb);    // tile 2it   (db0), prefetch 2it+1
        TILE(1, n2, fBb, fBa);    // tile 2it+1 (db1), prefetch 2it+2
    }
#undef TILE
#undef HMFMA
#undef LOADB
#undef LDAF
#undef STAGEH
#undef VMC0
#undef LG0
#undef BAR
#undef PRIO

    // ---- epilogue: C/D mapping col=lane&15, row=(lane>>4)*4+reg ----
#pragma unroll
    for (int m = 0; m < 8; ++m) {
        const int row = bm * 256 + wr * 128 + m * 16 + lq * 4;
#pragma unroll
        for (int n = 0; n < 4; ++n) {
            const int col = bn * 256 + wc * 64 + n * 16 + l15;
            const float bv = bias[col];
#pragma unroll
            for (int r = 0; r < 4; ++r) {
                C[(size_t)(row + r) * N + col] = acc[m][n][r] + bv;
            }
        }
    }
}

extern "C" void kernel_launch(void* const* d_in, const int* in_sizes, int n_in,
                              void* d_out, int out_size, void* d_ws, size_t ws_size,
                              hipStream_t stream) {
    const float* x    = (const float*)d_in[0];   // [4,2048,2048]
    const float* w    = (const float*)d_in[1];   // [8192,2048]
    const float* bias = (const float*)d_in[2];   // [8192]
    const float* las  = (const float*)d_in[3];   // log_act_s [1]
    const float* laq  = (const float*)d_in[4];   // log_act_q [1]
    const float* ab   = (const float*)d_in[5];   // act_b [1]
    const float* lws  = (const float*)d_in[6];   // log_wght_s [8192]
    float* out = (float*)d_out;

    constexpr size_t MK = (size_t)8192 * 2048;
    _Float16* xq = (_Float16*)d_ws;
    _Float16* wq = (_Float16*)((char*)d_ws + MK * sizeof(_Float16));

    quant_kernel<<<16384, 256, 0, stream>>>(x, las, laq, ab, w, lws, xq, wq);
    gemm_kernel<<<1024, 512, 0, stream>>>(xq, wq, bias, out);
}

// Round 18
// 278.961 us; speedup vs baseline: 1.5668x; 1.5668x over previous
//
#include <hip/hip_runtime.h>
#include <hip/hip_bf16.h>

// NoisyActLin: y = fakequant(x) @ fakequant(W).T + bias
// x: [4,2048,2048] f32 -> M=8192, K=2048 ; W: [8192,2048] f32 -> N=8192
// out: [8192, 8192] f32
//
// R18: fat K-tile with ZERO manual waits inside the tile.
// Root cause found (R10/R17 post-mortem): inline asm with a "memory"
// clobber forces the compiler to insert a full lgkmcnt(0) BEFORE the asm —
// so every hand-written counted lgkm wait was preceded by a hidden full
// drain, serializing port and MFMA in all of R5..R16 (44-48% MfmaUtil).
// Fix = m97 mechanism: leave ds_read->MFMA scheduling entirely to the
// compiler (it emits counted lgkmcnt(4/3/1/0) — guide §5, m97 asm dump).
// Per K-tile: STAGET(next) ; 24 ds_reads ; 64 MFMA ; vmcnt(0)"memory" ; BAR.
// Port head ~1150cyc exposed, remaining ~1150cyc drains under 2x1241cyc
// MFMA issue -> ~3900 cyc/K-tile vs 4743 serialized.
// Keeps: T2 swizzle (0 conflicts), R13 XCD map (FETCH 197MB), R9 wait
// discipline (lands-guarantee = own-wave vmcnt(0) BEFORE barrier).

using f16x8 = __attribute__((ext_vector_type(8))) _Float16;
using f32x4 = __attribute__((ext_vector_type(4))) float;

#define AS1 __attribute__((address_space(1)))
#define AS3 __attribute__((address_space(3)))

static __device__ __forceinline__ void gload_lds16(const void* g, void* l) {
    __builtin_amdgcn_global_load_lds((const AS1 void*)g, (AS3 void*)l, 16, 0, 0);
}

// ---------------- fused fake-quant: x elementwise + W per-row ----------------
__global__ __launch_bounds__(256) void quant_kernel(
    const float* __restrict__ X,
    const float* __restrict__ las, const float* __restrict__ laq,
    const float* __restrict__ ab,
    const float* __restrict__ W, const float* __restrict__ lws,
    _Float16* __restrict__ Xq, _Float16* __restrict__ Wq) {
    constexpr int K = 2048;
    __shared__ float smn[4], smx[4];
    const int t = threadIdx.x;

    if (blockIdx.x < 8192) {
        const float ls = las[0], lq = laq[0];
        const float s = exp2f(ls);
        const float rs = exp2f(-ls);
        const float q = exp2f(lq);
        const float zp = rintf(ab[0] * rs * 2.0f) * 0.5f * s;  // ACT_GUARD=2
        const float lo = zp;
        const float hi = (zp + q) - s;

        const size_t base = ((size_t)blockIdx.x * 256 + t) * 8;
        float4 v0 = *(const float4*)&X[base];
        float4 v1 = *(const float4*)&X[base + 4];
        float vals[8] = {v0.x, v0.y, v0.z, v0.w, v1.x, v1.y, v1.z, v1.w};

        f16x8 out;
#pragma unroll
        for (int i = 0; i < 8; ++i) {
            float c = fminf(fmaxf(vals[i], lo), hi);
            float qx = rintf((c - zp) * rs);
            out[i] = (_Float16)(qx * s + zp);
        }
        *(f16x8*)&Xq[base] = out;
    } else {
        const int row = blockIdx.x - 8192;
        const float* w = W + (size_t)row * K;

        float4 v0 = ((const float4*)w)[t * 2];
        float4 v1 = ((const float4*)w)[t * 2 + 1];
        float vals[8] = {v0.x, v0.y, v0.z, v0.w, v1.x, v1.y, v1.z, v1.w};

        float mn = vals[0], mx = vals[0];
#pragma unroll
        for (int i = 1; i < 8; ++i) {
            mn = fminf(mn, vals[i]);
            mx = fmaxf(mx, vals[i]);
        }
#pragma unroll
        for (int off = 32; off >= 1; off >>= 1) {
            mn = fminf(mn, __shfl_xor(mn, off));
            mx = fmaxf(mx, __shfl_xor(mx, off));
        }
        if ((t & 63) == 0) { smn[t >> 6] = mn; smx[t >> 6] = mx; }
        __syncthreads();
        mn = fminf(fminf(smn[0], smn[1]), fminf(smn[2], smn[3]));
        mx = fmaxf(fmaxf(smx[0], smx[1]), fmaxf(smx[2], smx[3]));

        const float l = lws[row];
        const float ws = exp2f(l);
        const float rs = exp2f(-l);
        const float qwmin = rintf(mn * rs * 2.0f) * 0.5f * ws;  // WGT_GUARD=2
        const float qwmax = rintf(mx * rs * 2.0f) * 0.5f * ws;

        f16x8 out;
#pragma unroll
        for (int i = 0; i < 8; ++i) {
            float c = fminf(fmaxf(vals[i], qwmin), qwmax);
            float qw = rintf((c - qwmin) * rs);
            out[i] = (_Float16)(qw * ws + qwmin);
        }
        *(f16x8*)&Wq[(size_t)row * K + (size_t)t * 8] = out;
    }
}

// ---------------- GEMM: C[M][N] = A[M][K] * B[N][K]^T + bias ----------------
// LDS: A [db2][half2][128][64] f16 at 0 (64KB), B same at +65536 (128KB).
// 8 waves (2Mx4N), 128x64 per wave. One fat phase per K-tile (32 total):
//   STAGET(db^1, kt+1)    8 gload_lds (tile kt+1)
//   24 ds_read_b128       (tile kt; ks-grouped; compiler-scheduled)
//   64 MFMA               (ks0 cluster, ks1 cluster; compiler lgkm waits)
//   vmcnt(0) "memory"     own stages drained BEFORE barrier (R9 rule);
//                         clobber also pins next tile's reads below
//   s_barrier             => all waves' tile-(kt+1) data landed
// WAR: STAGET targets tile kt-1's slots; every wave's kt-1 reads retired
// before its last kt-1 MFMA issued (compiler data-dep waits), hence before
// it passed the kt-1 end barrier. Last-iter clamp re-stages (benign).
__global__ __launch_bounds__(512, 2) void gemm_kernel(
    const _Float16* __restrict__ A, const _Float16* __restrict__ B,
    const float* __restrict__ bias, float* __restrict__ C) {
    constexpr int N = 8192, K = 2048;
    constexpr int KT = K / 64;          // 32 K-tiles
    __shared__ char smem[131072];       // A: 0..64K, B: 64K..128K

    // L2/L3-aware mapping (R13): XCD x owns A-band [4x,4x+4); bm fastest.
    const int bid = blockIdx.x;
    const int j = bid >> 3;
    const int bm = (bid & 7) * 4 + (j & 3);
    const int bn = j >> 2;

    const int t = threadIdx.x;
    const int lane = t & 63;
    const int wid = t >> 6;
    const int wr = wid >> 2;            // 0..1 (M half)
    const int wc = wid & 3;             // 0..3 (N quarter)
    const int l15 = lane & 15;
    const int lq = lane >> 4;

    // staging: half-tile [128][64] f16 = 16KB, linear dest, pre-swizzled
    // source. T2 swizzle: byte ^= (row&7)<<4 (verified 0 conflicts).
    const int d0 = t * 16, d1 = d0 + 8192;
    const int r0 = d0 >> 7, c0 = (((d0 & 127) ^ (((d0 >> 7) & 7) << 4)) >> 1);
    const int r1 = d1 >> 7, c1 = (((d1 & 127) ^ (((d1 >> 7) & 7) << 4)) >> 1);
    const _Float16* Agb = A + (size_t)bm * 256 * K;
    const _Float16* Bgb = B + (size_t)bn * 256 * K;

    // read-side swizzled k-col byte offsets (frag row&7 == l15&7)
    const int cp0 = (lq * 16) ^ ((l15 & 7) << 4);
    const int cp1 = cp0 ^ 64;           // second K-half (bit6 XOR)

    f32x4 acc[8][4] = {};
    f16x8 fA[8][2], fB[4][2];

#define STAGEH(GB, RO, DBS, H, KS) do {                                        \
        const _Float16* _g = (GB) + (size_t)((H) * 128) * K + (size_t)(KS) * 64;\
        char* _l = smem + (RO) + ((DBS) * 2 + (H)) * 16384;                    \
        gload_lds16(_g + (size_t)r0 * K + c0, _l + d0);                        \
        gload_lds16(_g + (size_t)r1 * K + c1, _l + d1);                        \
    } while (0)

#define STAGET(DBS, KS) do {                                                   \
        STAGEH(Agb, 0,     DBS, 0, KS);                                        \
        STAGEH(Agb, 0,     DBS, 1, KS);                                        \
        STAGEH(Bgb, 65536, DBS, 0, KS);                                        \
        STAGEH(Bgb, 65536, DBS, 1, KS);                                        \
    } while (0)

    // ---- prologue: stage tile 0 into db0; drain BEFORE barrier ----
    STAGET(0, 0);
    asm volatile("s_waitcnt vmcnt(0)" ::: "memory");
    __builtin_amdgcn_s_barrier();

    for (int kt = 0; kt < KT; ++kt) {
        const int db = kt & 1;
        const int nx = (kt + 1 < KT) ? kt + 1 : KT - 1;

        STAGET(db ^ 1, nx);              // 8 loads for tile kt+1

        // 24 ds_read_b128 of tile kt (ks-grouped; NO manual waits — the
        // compiler emits counted lgkm before each dependent MFMA)
        const char* _a = smem + (db * 2 + wr) * 16384 + l15 * 128;
        const char* _b = smem + 65536 + (db * 2 + (wc >> 1)) * 16384 +
                         (wc & 1) * 8192 + l15 * 128;
#pragma unroll
        for (int m = 0; m < 8; ++m)
            fA[m][0] = *(const f16x8*)(_a + m * 2048 + cp0);
#pragma unroll
        for (int n = 0; n < 4; ++n)
            fB[n][0] = *(const f16x8*)(_b + n * 2048 + cp0);
#pragma unroll
        for (int m = 0; m < 8; ++m)
            fA[m][1] = *(const f16x8*)(_a + m * 2048 + cp1);
#pragma unroll
        for (int n = 0; n < 4; ++n)
            fB[n][1] = *(const f16x8*)(_b + n * 2048 + cp1);

        // ks0 cluster then ks1 cluster — pure data deps
#pragma unroll
        for (int m = 0; m < 8; ++m)
#pragma unroll
            for (int n = 0; n < 4; ++n)
                acc[m][n] = __builtin_amdgcn_mfma_f32_16x16x32_f16(
                    fA[m][0], fB[n][0], acc[m][n], 0, 0, 0);
#pragma unroll
        for (int m = 0; m < 8; ++m)
#pragma unroll
            for (int n = 0; n < 4; ++n)
                acc[m][n] = __builtin_amdgcn_mfma_f32_16x16x32_f16(
                    fA[m][1], fB[n][1], acc[m][n], 0, 0, 0);

        asm volatile("s_waitcnt vmcnt(0)" ::: "memory");  // own stages landed
        __builtin_amdgcn_s_barrier();    // => all waves' stages landed
    }
#undef STAGEH
#undef STAGET

    // ---- epilogue: C/D mapping col=lane&15, row=(lane>>4)*4+reg ----
#pragma unroll
    for (int m = 0; m < 8; ++m) {
        const int row = bm * 256 + wr * 128 + m * 16 + lq * 4;
#pragma unroll
        for (int n = 0; n < 4; ++n) {
            const int col = bn * 256 + wc * 64 + n * 16 + l15;
            const float bv = bias[col];
#pragma unroll
            for (int r = 0; r < 4; ++r) {
                C[(size_t)(row + r) * N + col] = acc[m][n][r] + bv;
            }
        }
    }
}

extern "C" void kernel_launch(void* const* d_in, const int* in_sizes, int n_in,
                              void* d_out, int out_size, void* d_ws, size_t ws_size,
                              hipStream_t stream) {
    const float* x    = (const float*)d_in[0];   // [4,2048,2048]
    const float* w    = (const float*)d_in[1];   // [8192,2048]
    const float* bias = (const float*)d_in[2];   // [8192]
    const float* las  = (const float*)d_in[3];   // log_act_s [1]
    const float* laq  = (const float*)d_in[4];   // log_act_q [1]
    const float* ab   = (const float*)d_in[5];   // act_b [1]
    const float* lws  = (const float*)d_in[6];   // log_wght_s [8192]
    float* out = (float*)d_out;

    constexpr size_t MK = (size_t)8192 * 2048;
    _Float16* xq = (_Float16*)d_ws;
    _Float16* wq = (_Float16*)((char*)d_ws + MK * sizeof(_Float16));

    quant_kernel<<<16384, 256, 0, stream>>>(x, las, laq, ab, w, lws, xq, wq);
    gemm_kernel<<<1024, 512, 0, stream>>>(xq, wq, bias, out);
}